// Round 5
// baseline (479.114 us; speedup 1.0000x reference)
//
#include <hip/hip_runtime.h>
#include <hip/hip_bf16.h>
#include <stdint.h>

// Problem constants (B=4, T=2048, D=H=1024, E=8, topn=2)
#define TOKENS   8192
#define DDIM     1024
#define EXPERTS  8
#define NSLOT    (TOKENS * 2)   // every token picks exactly 2 experts
#define MAXT     72             // >= max sum over e of ceil(ne/256) (71)

typedef __bf16 bf16x8_t __attribute__((ext_vector_type(8)));
typedef __bf16 bf16x4_t __attribute__((ext_vector_type(4)));
typedef float  f32x4_t  __attribute__((ext_vector_type(4)));

// ---------------------------------------------------------------------------
// async global->LDS, 16B per lane; LDS dest is wave-uniform base (HW adds
// lane*16).
__device__ __forceinline__ void gl_lds16(const void* g, void* l) {
  __builtin_amdgcn_global_load_lds(
      (const __attribute__((address_space(1))) void*)g,
      (__attribute__((address_space(3))) void*)l, 16, 0, 0);
}

// ---------------------------------------------------------------------------
// Weight transpose + convert: w[e][k][n] fp32 -> wT[e][n][k] bf16.
// r4 rework: 256k x 64n tiles, 1536 blocks (was 12288 tiny blocks), float4
// reads, LDS transpose, 16B coalesced bf16 stores.
__global__ __launch_bounds__(256) void twt_k(
    const float* __restrict__ w1, const float* __restrict__ w2,
    const float* __restrict__ w3, __bf16* __restrict__ w1T,
    __bf16* __restrict__ w2T, __bf16* __restrict__ w3T) {
  __shared__ __bf16 lt[64][264];  // [n][k], k padded 256->264 (16B-mult rows)
  const int layer = blockIdx.z >> 3, e = blockIdx.z & 7;
  const float* w = (layer == 0) ? w1 : (layer == 1) ? w2 : w3;
  __bf16* wT = (layer == 0) ? w1T : (layer == 1) ? w2T : w3T;
  const size_t ebase = (size_t)e << 20;
  const int kb = blockIdx.x * 256, nb = blockIdx.y * 64;
  const int tid = threadIdx.x;
  const float* src = w + ebase + (size_t)kb * 1024 + nb;
  const int rr = tid >> 4;   // 0..15 (k row within pass)
  const int c4 = tid & 15;   // float4 col index (4 n each)
#pragma unroll
  for (int pass = 0; pass < 16; ++pass) {
    const int k = pass * 16 + rr;
    const float4 v = *(const float4*)(src + (size_t)k * 1024 + c4 * 4);
    const int n = c4 * 4;
    lt[n + 0][k] = (__bf16)v.x;
    lt[n + 1][k] = (__bf16)v.y;
    lt[n + 2][k] = (__bf16)v.z;
    lt[n + 3][k] = (__bf16)v.w;
  }
  __syncthreads();
  __bf16* dst = wT + ebase + (size_t)nb * 1024 + kb;
  const int n8 = tid >> 5;   // 0..7
  const int l16 = tid & 31;  // 16B chunk within 512B row
#pragma unroll
  for (int pass = 0; pass < 8; ++pass) {
    const int n = pass * 8 + n8;
    const bf16x8_t v = *(const bf16x8_t*)(&lt[n][l16 * 8]);
    *(bf16x8_t*)(dst + (size_t)n * 1024 + l16 * 8) = v;
  }
}

// ---------------------------------------------------------------------------
// Gating + x->bf16 convert fused: one wave per token, no atomics.
// Weights = softmax over the two top logits (L1-renorm cancels denominator).
__global__ __launch_bounds__(256) void gate_k(
    const float* __restrict__ x, const float* __restrict__ gw,
    const float* __restrict__ gb, __bf16* __restrict__ xbf,
    int* __restrict__ top_i, float* __restrict__ top_w) {
  const int t = blockIdx.x * 4 + (threadIdx.x >> 6);
  const int lane = threadIdx.x & 63;
  const float4* x4 = (const float4*)(x + (size_t)t * DDIM);
  bf16x4_t* xo4 = (bf16x4_t*)(xbf + (size_t)t * DDIM);
  const float4* g4 = (const float4*)gw;
  float acc[EXPERTS];
#pragma unroll
  for (int e = 0; e < EXPERTS; ++e) acc[e] = 0.f;
#pragma unroll
  for (int d4 = lane; d4 < 256; d4 += 64) {
    const float4 v = x4[d4];
    bf16x4_t o = {(__bf16)v.x, (__bf16)v.y, (__bf16)v.z, (__bf16)v.w};
    xo4[d4] = o;
    const float4* g = g4 + (size_t)d4 * 8;  // rows 4*d4..4*d4+3, 2 float4 each
    float4 ga, gbv;
    ga = g[0]; gbv = g[1];
    acc[0] += v.x * ga.x; acc[1] += v.x * ga.y; acc[2] += v.x * ga.z; acc[3] += v.x * ga.w;
    acc[4] += v.x * gbv.x; acc[5] += v.x * gbv.y; acc[6] += v.x * gbv.z; acc[7] += v.x * gbv.w;
    ga = g[2]; gbv = g[3];
    acc[0] += v.y * ga.x; acc[1] += v.y * ga.y; acc[2] += v.y * ga.z; acc[3] += v.y * ga.w;
    acc[4] += v.y * gbv.x; acc[5] += v.y * gbv.y; acc[6] += v.y * gbv.z; acc[7] += v.y * gbv.w;
    ga = g[4]; gbv = g[5];
    acc[0] += v.z * ga.x; acc[1] += v.z * ga.y; acc[2] += v.z * ga.z; acc[3] += v.z * ga.w;
    acc[4] += v.z * gbv.x; acc[5] += v.z * gbv.y; acc[6] += v.z * gbv.z; acc[7] += v.z * gbv.w;
    ga = g[6]; gbv = g[7];
    acc[0] += v.w * ga.x; acc[1] += v.w * ga.y; acc[2] += v.w * ga.z; acc[3] += v.w * ga.w;
    acc[4] += v.w * gbv.x; acc[5] += v.w * gbv.y; acc[6] += v.w * gbv.z; acc[7] += v.w * gbv.w;
  }
#pragma unroll
  for (int e = 0; e < EXPERTS; ++e)
    for (int s = 32; s > 0; s >>= 1) acc[e] += __shfl_down(acc[e], s);
  if (lane == 0) {
#pragma unroll
    for (int e = 0; e < EXPERTS; ++e) acc[e] += gb[e];
    int i1 = 0;
    for (int e = 1; e < EXPERTS; ++e)
      if (acc[e] > acc[i1]) i1 = e;
    int i2 = (i1 == 0) ? 1 : 0;
    for (int e = 0; e < EXPERTS; ++e)
      if (e != i1 && acc[e] > acc[i2]) i2 = e;
    const float r = expf(acc[i2] - acc[i1]);  // <= 1
    const float wA = 1.f / (1.f + r);
    const float wB = r / (1.f + r);
    top_i[t * 2] = i1; top_i[t * 2 + 1] = i2;
    top_w[t * 2] = wA; top_w[t * 2 + 1] = wB;
  }
}

// ---------------------------------------------------------------------------
// Routing plan: ONE block, 1024 threads. Stable counting-sort of the 16384
// (token,expert) entries; zero global atomics, deterministic. Emits the GEMM
// tile work-list (256-row m-tiles) as int4 {e, m0, off, ne}.
__global__ __launch_bounds__(1024) void plan_k(
    const int* __restrict__ top_i, int* __restrict__ eoff,
    int* __restrict__ tok_list, int* __restrict__ slot_of,
    int4* __restrict__ work, int* __restrict__ ntiles) {
  const int tid = threadIdx.x;
  const int lane = tid & 63, wid = tid >> 6;  // 16 waves
  __shared__ int ws[16][EXPERTS];   // per-wave totals -> per-wave bases
  __shared__ int eoff_s[EXPERTS];
  __shared__ int base_lds[1024 * EXPERTS];  // 32 KB

  int ids[16];
  unsigned long long h64 = 0;
#pragma unroll
  for (int j = 0; j < 16; ++j) {
    ids[j] = top_i[tid * 16 + j];
    h64 += 1ull << (ids[j] * 8);
  }
#pragma unroll
  for (int e = 0; e < EXPERTS; ++e) {
    const int h = (int)((h64 >> (8 * e)) & 0xff);
    int v = h;
    for (int s = 1; s < 64; s <<= 1) {
      const int u = __shfl_up(v, s);
      if (lane >= s) v += u;
    }
    const int excl = v - h;
    const int tot = __shfl(v, 63);
    if (lane == 0) ws[wid][e] = tot;
    base_lds[tid * EXPERTS + e] = excl;
  }
  __syncthreads();
  if (tid == 0) {
    int tot[EXPERTS];
    for (int e = 0; e < EXPERTS; ++e) {
      int run = 0;
      for (int w = 0; w < 16; ++w) { const int c = ws[w][e]; ws[w][e] = run; run += c; }
      tot[e] = run;
    }
    int s = 0, nt = 0;
    for (int e = 0; e < EXPERTS; ++e) {
      const int te = tot[e];
      eoff_s[e] = s; eoff[e] = s;
      const int mt = (te + 255) >> 8;
      for (int i = 0; i < mt; ++i) { work[nt] = make_int4(e, i << 8, s, te); ++nt; }
      s += te;
    }
    eoff[EXPERTS] = s;  // == NSLOT
    ntiles[0] = nt;
  }
  __syncthreads();
#pragma unroll
  for (int e = 0; e < EXPERTS; ++e)
    base_lds[tid * EXPERTS + e] += eoff_s[e] + ws[wid][e];
  unsigned long long pre64 = 0;
#pragma unroll
  for (int j = 0; j < 16; ++j) {
    const int entry = tid * 16 + j;
    const int e = ids[j];
    const int pre = (int)((pre64 >> (8 * e)) & 0xff);
    pre64 += 1ull << (8 * e);
    const int s = base_lds[tid * EXPERTS + e] + pre;
    tok_list[s] = entry >> 1;  // token index
    slot_of[entry] = s;
  }
}

// ---------------------------------------------------------------------------
// Per-expert GEMM: 256x256 tile, 8 waves (2M x 4N), BK=64 (two verified
// 256x32 XOR-swizzled subtiles), mfma_f32_16x16x32_bf16, per-wave out 128x64.
// 8-PHASE SCHEDULE (m201/T3+T4+T5 template; r4 post-mortem: the 2-phase
// stage->vmcnt->barrier convoy is a structural ~70% stall — MfmaUtil pinned
// at 17.5% across 3 structures). Per K-tile: 4 phases, each =
//   [stage/ds_read] barrier; lgkmcnt(0); setprio(1); 16 MFMA (one C
//   quadrant); setprio(0); barrier.
// Counted vmcnt(4) ONCE per tile (phase 1), never 0 in the main loop.
// Ledger: stage(t+1) issues at tile t phases 1-2 (4+4 loads) into buf^1;
// waited at tile t+1 phase 1 with exactly 4 newer loads outstanding.
// Buffer overwrite vs last reads of buf^1 (tile t-1 P3/P4) separated by the
// t-1 P4 closing barrier. LDS 2 dbuf x (A 32K + B 32K) = 128 KB, 1 block/CU.
// MFMA operands SWAPPED (mfma(B,A) -> C^T in regs): 8B vector C stores.
// GATHER: A row = tok_list[off+m]; else off+m.
template <int GATHER, int LEAKY>
__global__ __launch_bounds__(512, 2) void moe_gemm(
    const __bf16* __restrict__ A, const int* __restrict__ tok,
    const __bf16* __restrict__ W, const float* __restrict__ bias,
    const int4* __restrict__ work, const int* __restrict__ ntiles,
    __bf16* __restrict__ out) {
  if ((int)blockIdx.y >= ntiles[0]) return;
  const int4 wk = work[blockIdx.y];
  const int e = wk.x;
  const int m0 = wk.y;
  const int off = wk.z;
  const int ne = wk.w;
  const int n0 = blockIdx.x * 256;

  // [buf][kslice][256*32] — each kslice is the r2/r4-verified swizzled tile.
  __shared__ __align__(16) __bf16 As[2][2][256 * 32];
  __shared__ __align__(16) __bf16 Bs[2][2][256 * 32];

  const int tid = threadIdx.x;
  const int lane = tid & 63;
  const int wid = tid >> 6;          // 0..7
  const int wm = wid >> 2, wn = wid & 3;
  const int ln = lane & 15, quad = lane >> 4;

  // Staging: chunk c in [0,1024) -> tile row c>>2, physical k-slot c&3 holds
  // logical k-chunk kc = (c&3) ^ ((row>>1)&3)  (XOR swizzle).
  const __bf16* aptr[2];
  const __bf16* bptr[2];
#pragma unroll
  for (int j = 0; j < 2; ++j) {
    const int c = (wid * 2 + j) * 64 + lane;  // 0..1023
    const int row = c >> 2;                   // 0..255
    const int kc = (c & 3) ^ ((row >> 1) & 3);
    int r = m0 + row;
    if (r >= ne) r = m0;  // clamp: garbage rows computed but never stored
    const long arow = GATHER ? (long)tok[off + r] : (long)(off + r);
    aptr[j] = A + arow * DDIM + kc * 8;
    bptr[j] = W + ((long)e << 20) + (long)(n0 + row) * 1024 + kc * 8;
  }
  const int st0 = (wid * 2) * 512;      // wave-uniform LDS element offsets
  const int st1 = (wid * 2 + 1) * 512;  // (each gl_lds16 covers 512 elems)

  // Fragment-read swizzle (verified r2/r4): physical slot quad^((ln>>1)&3).
  const int swz = (quad ^ ((ln >> 1) & 3)) * 8;

  const f32x4_t vzero = {0.f, 0.f, 0.f, 0.f};
  f32x4_t acc[8][4];
#pragma unroll
  for (int i = 0; i < 8; ++i)
#pragma unroll
    for (int j = 0; j < 4; ++j) acc[i][j] = vzero;

#define SA(BUF, S, KT)                                            \
  do {                                                            \
    const int ko_ = (KT) * 64 + (S) * 32;                         \
    gl_lds16(aptr[0] + ko_, (__bf16*)As[BUF][S] + st0);           \
    gl_lds16(aptr[1] + ko_, (__bf16*)As[BUF][S] + st1);           \
  } while (0)
#define SB(BUF, S, KT)                                            \
  do {                                                            \
    const int ko_ = (KT) * 64 + (S) * 32;                         \
    gl_lds16(bptr[0] + ko_, (__bf16*)Bs[BUF][S] + st0);           \
    gl_lds16(bptr[1] + ko_, (__bf16*)Bs[BUF][S] + st1);           \
  } while (0)
#define WAITV(N) asm volatile("s_waitcnt vmcnt(" #N ")" ::: "memory")
#define LGKM0 asm volatile("s_waitcnt lgkmcnt(0)" ::: "memory")
#define BAR __builtin_amdgcn_s_barrier()

#define RDA(DST, BUF, I0)                                                     \
  _Pragma("unroll") for (int i2 = 0; i2 < 4; ++i2)                            \
  _Pragma("unroll") for (int s_ = 0; s_ < 2; ++s_)                            \
      DST[i2][s_] = *(const bf16x8_t*)(                                       \
          &As[BUF][s_][(wm * 128 + ((I0) + i2) * 16 + ln) * 32 + swz]);
#define RDB(DST, BUF, J0)                                                     \
  _Pragma("unroll") for (int j2 = 0; j2 < 2; ++j2)                            \
  _Pragma("unroll") for (int s_ = 0; s_ < 2; ++s_)                            \
      DST[j2][s_] = *(const bf16x8_t*)(                                       \
          &Bs[BUF][s_][(wn * 64 + ((J0) + j2) * 16 + ln) * 32 + swz]);
#define MM(AFR, I0, BFR, J0)                                                  \
  _Pragma("unroll") for (int i2 = 0; i2 < 4; ++i2)                            \
  _Pragma("unroll") for (int j2 = 0; j2 < 2; ++j2)                            \
  _Pragma("unroll") for (int s_ = 0; s_ < 2; ++s_)                            \
      acc[(I0) + i2][(J0) + j2] = __builtin_amdgcn_mfma_f32_16x16x32_bf16(    \
          BFR[j2][s_], AFR[i2][s_], acc[(I0) + i2][(J0) + j2], 0, 0, 0);

  // One K-tile (64), buffer B (literal), optionally staging tile T+1.
#define TILE(T, B, STG, VMN)                                                  \
  do {                                                                        \
    bf16x8_t a_[4][2], bl_[2][2], bh_[2][2];                                  \
    /* P1: stage A(T+1); wait stage(T); Q00 */                                \
    if (STG) { SA((B) ^ 1, 0, (T) + 1); SA((B) ^ 1, 1, (T) + 1); }            \
    WAITV(VMN);                                                               \
    BAR;                                                                      \
    RDA(a_, B, 0); RDB(bl_, B, 0);                                            \
    LGKM0;                                                                    \
    __builtin_amdgcn_s_setprio(1); MM(a_, 0, bl_, 0);                         \
    __builtin_amdgcn_s_setprio(0);                                            \
    BAR;                                                                      \
    /* P2: stage B(T+1); read bHi; Q01 */                                     \
    if (STG) { SB((B) ^ 1, 0, (T) + 1); SB((B) ^ 1, 1, (T) + 1); }            \
    RDB(bh_, B, 2);                                                           \
    BAR;                                                                      \
    LGKM0;                                                                    \
    __builtin_amdgcn_s_setprio(1); MM(a_, 0, bh_, 2);                         \
    __builtin_amdgcn_s_setprio(0);                                            \
    BAR;                                                                      \
    /* P3: read aHi; Q11 */                                                   \
    RDA(a_, B, 4);                                                            \
    BAR;                                                                      \
    LGKM0;                                                                    \
    __builtin_amdgcn_s_setprio(1); MM(a_, 4, bh_, 2);                         \
    __builtin_amdgcn_s_setprio(0);                                            \
    BAR;                                                                      \
    /* P4: re-read bLo; Q10 */                                                \
    RDB(bl_, B, 0);                                                           \
    BAR;                                                                      \
    LGKM0;                                                                    \
    __builtin_amdgcn_s_setprio(1); MM(a_, 4, bl_, 0);                         \
    __builtin_amdgcn_s_setprio(0);                                            \
    BAR;                                                                      \
  } while (0)

  // Prologue: stage tile 0 fully, drain, publish.
  SA(0, 0, 0); SA(0, 1, 0); SB(0, 0, 0); SB(0, 1, 0);
  WAITV(0);
  BAR;

  // 16 K-tiles; buffer index compile-time via x2 unroll. Tiles 0..13 stage
  // t+1; tile 14 stages 15; tile 15 is the tail (no stage, drain).
#pragma unroll 1
  for (int t = 0; t < 14; t += 2) {
    TILE(t, 0, 1, 4);
    TILE(t + 1, 1, 1, 4);
  }
  TILE(14, 0, 1, 4);
  TILE(15, 1, 0, 0);

#undef SA
#undef SB
#undef WAITV
#undef LGKM0
#undef BAR
#undef RDA
#undef RDB
#undef MM
#undef TILE

  // Epilogue. Swapped-operand D layout: lane ln = output row (m), quad*4+r =
  // output col (n) within each 16x16 fragment -> 8B stores.
  const float* bs = bias + (e << 10);
  const int nb = n0 + wn * 64 + quad * 4;
  float4 bv[4];
#pragma unroll
  for (int j = 0; j < 4; ++j) bv[j] = *(const float4*)(bs + nb + j * 16);
#pragma unroll
  for (int i = 0; i < 8; ++i) {
    const int m = m0 + wm * 128 + i * 16 + ln;
    if (m < ne) {
      __bf16* orow = out + (size_t)(off + m) * 1024 + nb;
#pragma unroll
      for (int j = 0; j < 4; ++j) {
        float t0 = acc[i][j][0] + bv[j].x;
        float t1 = acc[i][j][1] + bv[j].y;
        float t2 = acc[i][j][2] + bv[j].z;
        float t3 = acc[i][j][3] + bv[j].w;
        if (LEAKY) {
          t0 = (t0 >= 0.f) ? t0 : 0.01f * t0;
          t1 = (t1 >= 0.f) ? t1 : 0.01f * t1;
          t2 = (t2 >= 0.f) ? t2 : 0.01f * t2;
          t3 = (t3 >= 0.f) ? t3 : 0.01f * t3;
        }
        bf16x4_t pk = {(__bf16)t0, (__bf16)t1, (__bf16)t2, (__bf16)t3};
        *(bf16x4_t*)(orow + j * 16) = pk;
      }
    }
  }
}

// ---------------------------------------------------------------------------
// Final combine: out[t] = wA*eo[slotA] + wB*eo[slotB]  (eo is bf16).
// r4 rework: 2048 blocks (4 tokens/block, one wave each), 16B loads.
__global__ __launch_bounds__(256) void combine_k(
    const __bf16* __restrict__ eo, const int* __restrict__ slot_of,
    const float* __restrict__ top_w, float* __restrict__ out) {
  const int t = blockIdx.x * 4 + (threadIdx.x >> 6);
  const int lane = threadIdx.x & 63;
  const int s1 = slot_of[t * 2], s2 = slot_of[t * 2 + 1];
  const float w1 = top_w[t * 2], w2 = top_w[t * 2 + 1];
  const bf16x8_t* r1 = (const bf16x8_t*)(eo + (size_t)s1 * DDIM);
  const bf16x8_t* r2 = (const bf16x8_t*)(eo + (size_t)s2 * DDIM);
  float4* o4 = (float4*)(out + (size_t)t * DDIM);
#pragma unroll
  for (int i = 0; i < 2; ++i) {
    const int idx = lane * 2 + i;  // bf16x8 chunk 0..127
    const bf16x8_t a = r1[idx];
    const bf16x8_t b = r2[idx];
    float4 o0, o1;
    o0.x = w1 * (float)a[0] + w2 * (float)b[0];
    o0.y = w1 * (float)a[1] + w2 * (float)b[1];
    o0.z = w1 * (float)a[2] + w2 * (float)b[2];
    o0.w = w1 * (float)a[3] + w2 * (float)b[3];
    o1.x = w1 * (float)a[4] + w2 * (float)b[4];
    o1.y = w1 * (float)a[5] + w2 * (float)b[5];
    o1.z = w1 * (float)a[6] + w2 * (float)b[6];
    o1.w = w1 * (float)a[7] + w2 * (float)b[7];
    o4[idx * 2] = o0;
    o4[idx * 2 + 1] = o1;
  }
}

// ---------------------------------------------------------------------------
extern "C" void kernel_launch(void* const* d_in, const int* in_sizes, int n_in,
                              void* d_out, int out_size, void* d_ws,
                              size_t ws_size, hipStream_t stream) {
  (void)in_sizes; (void)n_in; (void)out_size; (void)ws_size;
  const float* x  = (const float*)d_in[0];
  const float* gw = (const float*)d_in[1];
  const float* gb = (const float*)d_in[2];
  const float* w1 = (const float*)d_in[3];
  const float* b1 = (const float*)d_in[4];
  const float* w2 = (const float*)d_in[5];
  const float* b2 = (const float*)d_in[6];
  const float* w3 = (const float*)d_in[7];
  const float* b3 = (const float*)d_in[8];
  float* out = (float*)d_out;

  // Workspace carve-up (~150 MB total).
  uint8_t* p = (uint8_t*)d_ws;
  auto alloc = [&](size_t b) {
    uint8_t* r = p;
    p += (b + 255) & ~(size_t)255;
    return r;
  };
  int*    eoff     = (int*)alloc(4 * (EXPERTS + 1));
  int*    ntiles   = (int*)alloc(4);
  int4*   work     = (int4*)alloc(16 * MAXT);
  int*    top_i    = (int*)alloc(4ull * TOKENS * 2);
  float*  top_w    = (float*)alloc(4ull * TOKENS * 2);
  int*    slot_of  = (int*)alloc(4ull * TOKENS * 2);
  int*    tok_list = (int*)alloc(4ull * NSLOT);
  __bf16* xbf      = (__bf16*)alloc(2ull * TOKENS * DDIM);
  __bf16* w1T      = (__bf16*)alloc(2ull * EXPERTS * 1024 * 1024);
  __bf16* w2T      = (__bf16*)alloc(2ull * EXPERTS * 1024 * 1024);
  __bf16* w3T      = (__bf16*)alloc(2ull * EXPERTS * 1024 * 1024);
  __bf16* h1       = (__bf16*)alloc(2ull * NSLOT * 1024);
  __bf16* h2       = (__bf16*)alloc(2ull * NSLOT * 1024);
  __bf16* eo       = (__bf16*)alloc(2ull * NSLOT * 1024);

  gate_k<<<TOKENS / 4, 256, 0, stream>>>(x, gw, gb, xbf, top_i, top_w);
  twt_k<<<dim3(4, 16, 24), 256, 0, stream>>>(w1, w2, w3, w1T, w2T, w3T);
  plan_k<<<1, 1024, 0, stream>>>(top_i, eoff, tok_list, slot_of, work, ntiles);

  moe_gemm<1, 1><<<dim3(4, MAXT), 512, 0, stream>>>(
      xbf, tok_list, w1T, b1, work, ntiles, h1);
  moe_gemm<0, 1><<<dim3(4, MAXT), 512, 0, stream>>>(
      h1, tok_list, w2T, b2, work, ntiles, h2);
  moe_gemm<0, 0><<<dim3(4, MAXT), 512, 0, stream>>>(
      h2, tok_list, w3T, b3, work, ntiles, eo);

  combine_k<<<TOKENS / 4, 256, 0, stream>>>(eo, slot_of, top_w, out);
}

// Round 6
// 421.162 us; speedup vs baseline: 1.1376x; 1.1376x over previous
//
#include <hip/hip_runtime.h>
#include <hip/hip_bf16.h>
#include <stdint.h>

// Problem constants (B=4, T=2048, D=H=1024, E=8, topn=2)
#define TOKENS   8192
#define DDIM     1024
#define EXPERTS  8
#define NSLOT    (TOKENS * 2)   // every token picks exactly 2 experts
#define MAXT     136            // >= max sum over e of ceil(ne/128) (135)

typedef __bf16 bf16x8_t __attribute__((ext_vector_type(8)));
typedef __bf16 bf16x4_t __attribute__((ext_vector_type(4)));
typedef float  f32x4_t  __attribute__((ext_vector_type(4)));

// ---------------------------------------------------------------------------
// async global->LDS, 16B per lane; LDS dest is wave-uniform base (HW adds
// lane*16).
__device__ __forceinline__ void gl_lds16(const void* g, void* l) {
  __builtin_amdgcn_global_load_lds(
      (const __attribute__((address_space(1))) void*)g,
      (__attribute__((address_space(3))) void*)l, 16, 0, 0);
}

// ---------------------------------------------------------------------------
// Weight transpose + convert: w[e][k][n] fp32 -> wT[e][n][k] bf16.
// 256k x 64n tiles, 1536 blocks, float4 reads, LDS transpose, 16B stores.
__global__ __launch_bounds__(256) void twt_k(
    const float* __restrict__ w1, const float* __restrict__ w2,
    const float* __restrict__ w3, __bf16* __restrict__ w1T,
    __bf16* __restrict__ w2T, __bf16* __restrict__ w3T) {
  __shared__ __bf16 lt[64][264];  // [n][k], k padded 256->264 (16B-mult rows)
  const int layer = blockIdx.z >> 3, e = blockIdx.z & 7;
  const float* w = (layer == 0) ? w1 : (layer == 1) ? w2 : w3;
  __bf16* wT = (layer == 0) ? w1T : (layer == 1) ? w2T : w3T;
  const size_t ebase = (size_t)e << 20;
  const int kb = blockIdx.x * 256, nb = blockIdx.y * 64;
  const int tid = threadIdx.x;
  const float* src = w + ebase + (size_t)kb * 1024 + nb;
  const int rr = tid >> 4;   // 0..15 (k row within pass)
  const int c4 = tid & 15;   // float4 col index (4 n each)
#pragma unroll
  for (int pass = 0; pass < 16; ++pass) {
    const int k = pass * 16 + rr;
    const float4 v = *(const float4*)(src + (size_t)k * 1024 + c4 * 4);
    const int n = c4 * 4;
    lt[n + 0][k] = (__bf16)v.x;
    lt[n + 1][k] = (__bf16)v.y;
    lt[n + 2][k] = (__bf16)v.z;
    lt[n + 3][k] = (__bf16)v.w;
  }
  __syncthreads();
  __bf16* dst = wT + ebase + (size_t)nb * 1024 + kb;
  const int n8 = tid >> 5;   // 0..7
  const int l16 = tid & 31;  // 16B chunk within 512B row
#pragma unroll
  for (int pass = 0; pass < 8; ++pass) {
    const int n = pass * 8 + n8;
    const bf16x8_t v = *(const bf16x8_t*)(&lt[n][l16 * 8]);
    *(bf16x8_t*)(dst + (size_t)n * 1024 + l16 * 8) = v;
  }
}

// ---------------------------------------------------------------------------
// Gating + x->bf16 convert fused: one wave per token, no atomics.
// Weights = softmax over the two top logits (L1-renorm cancels denominator).
__global__ __launch_bounds__(256) void gate_k(
    const float* __restrict__ x, const float* __restrict__ gw,
    const float* __restrict__ gb, __bf16* __restrict__ xbf,
    int* __restrict__ top_i, float* __restrict__ top_w) {
  const int t = blockIdx.x * 4 + (threadIdx.x >> 6);
  const int lane = threadIdx.x & 63;
  const float4* x4 = (const float4*)(x + (size_t)t * DDIM);
  bf16x4_t* xo4 = (bf16x4_t*)(xbf + (size_t)t * DDIM);
  const float4* g4 = (const float4*)gw;
  float acc[EXPERTS];
#pragma unroll
  for (int e = 0; e < EXPERTS; ++e) acc[e] = 0.f;
#pragma unroll
  for (int d4 = lane; d4 < 256; d4 += 64) {
    const float4 v = x4[d4];
    bf16x4_t o = {(__bf16)v.x, (__bf16)v.y, (__bf16)v.z, (__bf16)v.w};
    xo4[d4] = o;
    const float4* g = g4 + (size_t)d4 * 8;  // rows 4*d4..4*d4+3, 2 float4 each
    float4 ga, gbv;
    ga = g[0]; gbv = g[1];
    acc[0] += v.x * ga.x; acc[1] += v.x * ga.y; acc[2] += v.x * ga.z; acc[3] += v.x * ga.w;
    acc[4] += v.x * gbv.x; acc[5] += v.x * gbv.y; acc[6] += v.x * gbv.z; acc[7] += v.x * gbv.w;
    ga = g[2]; gbv = g[3];
    acc[0] += v.y * ga.x; acc[1] += v.y * ga.y; acc[2] += v.y * ga.z; acc[3] += v.y * ga.w;
    acc[4] += v.y * gbv.x; acc[5] += v.y * gbv.y; acc[6] += v.y * gbv.z; acc[7] += v.y * gbv.w;
    ga = g[4]; gbv = g[5];
    acc[0] += v.z * ga.x; acc[1] += v.z * ga.y; acc[2] += v.z * ga.z; acc[3] += v.z * ga.w;
    acc[4] += v.z * gbv.x; acc[5] += v.z * gbv.y; acc[6] += v.z * gbv.z; acc[7] += v.z * gbv.w;
    ga = g[6]; gbv = g[7];
    acc[0] += v.w * ga.x; acc[1] += v.w * ga.y; acc[2] += v.w * ga.z; acc[3] += v.w * ga.w;
    acc[4] += v.w * gbv.x; acc[5] += v.w * gbv.y; acc[6] += v.w * gbv.z; acc[7] += v.w * gbv.w;
  }
#pragma unroll
  for (int e = 0; e < EXPERTS; ++e)
    for (int s = 32; s > 0; s >>= 1) acc[e] += __shfl_down(acc[e], s);
  if (lane == 0) {
#pragma unroll
    for (int e = 0; e < EXPERTS; ++e) acc[e] += gb[e];
    int i1 = 0;
    for (int e = 1; e < EXPERTS; ++e)
      if (acc[e] > acc[i1]) i1 = e;
    int i2 = (i1 == 0) ? 1 : 0;
    for (int e = 0; e < EXPERTS; ++e)
      if (e != i1 && acc[e] > acc[i2]) i2 = e;
    const float r = expf(acc[i2] - acc[i1]);  // <= 1
    const float wA = 1.f / (1.f + r);
    const float wB = r / (1.f + r);
    top_i[t * 2] = i1; top_i[t * 2 + 1] = i2;
    top_w[t * 2] = wA; top_w[t * 2 + 1] = wB;
  }
}

// ---------------------------------------------------------------------------
// Routing plan: ONE block, 1024 threads. Stable counting-sort of the 16384
// (token,expert) entries; zero global atomics, deterministic. Emits the GEMM
// tile work-list (128-row m-tiles) as int4 {e, m0, off, ne}.
__global__ __launch_bounds__(1024) void plan_k(
    const int* __restrict__ top_i, int* __restrict__ eoff,
    int* __restrict__ tok_list, int* __restrict__ slot_of,
    int4* __restrict__ work, int* __restrict__ ntiles) {
  const int tid = threadIdx.x;
  const int lane = tid & 63, wid = tid >> 6;  // 16 waves
  __shared__ int ws[16][EXPERTS];   // per-wave totals -> per-wave bases
  __shared__ int eoff_s[EXPERTS];
  __shared__ int base_lds[1024 * EXPERTS];  // 32 KB

  int ids[16];
  unsigned long long h64 = 0;
#pragma unroll
  for (int j = 0; j < 16; ++j) {
    ids[j] = top_i[tid * 16 + j];
    h64 += 1ull << (ids[j] * 8);
  }
#pragma unroll
  for (int e = 0; e < EXPERTS; ++e) {
    const int h = (int)((h64 >> (8 * e)) & 0xff);
    int v = h;
    for (int s = 1; s < 64; s <<= 1) {
      const int u = __shfl_up(v, s);
      if (lane >= s) v += u;
    }
    const int excl = v - h;
    const int tot = __shfl(v, 63);
    if (lane == 0) ws[wid][e] = tot;
    base_lds[tid * EXPERTS + e] = excl;
  }
  __syncthreads();
  if (tid == 0) {
    int tot[EXPERTS];
    for (int e = 0; e < EXPERTS; ++e) {
      int run = 0;
      for (int w = 0; w < 16; ++w) { const int c = ws[w][e]; ws[w][e] = run; run += c; }
      tot[e] = run;
    }
    int s = 0, nt = 0;
    for (int e = 0; e < EXPERTS; ++e) {
      const int te = tot[e];
      eoff_s[e] = s; eoff[e] = s;
      const int mt = (te + 127) >> 7;
      for (int i = 0; i < mt; ++i) { work[nt] = make_int4(e, i << 7, s, te); ++nt; }
      s += te;
    }
    eoff[EXPERTS] = s;  // == NSLOT
    ntiles[0] = nt;
  }
  __syncthreads();
#pragma unroll
  for (int e = 0; e < EXPERTS; ++e)
    base_lds[tid * EXPERTS + e] += eoff_s[e] + ws[wid][e];
  unsigned long long pre64 = 0;
#pragma unroll
  for (int j = 0; j < 16; ++j) {
    const int entry = tid * 16 + j;
    const int e = ids[j];
    const int pre = (int)((pre64 >> (8 * e)) & 0xff);
    pre64 += 1ull << (8 * e);
    const int s = base_lds[tid * EXPERTS + e] + pre;
    tok_list[s] = entry >> 1;  // token index
    slot_of[entry] = s;
  }
}

// ---------------------------------------------------------------------------
// Per-expert GEMM: 128x256 tile (BM x BN), BK=32, mfma_f32_16x16x32_bf16,
// 8 waves (2M x 4N), per-wave out 64x64 (acc[4][4] = 64 VGPR).
// r5 post-mortem: 256^2 at 1 block/CU = per-tile eff 33% AND a 2-generation
// grid tail (272 blocks / 256 CUs) idling half the machine. This config:
//   - LDS 3buf x (A 8K + B 16K) = 72 KB  -> 2 blocks/CU co-resident
//     (16 waves/CU: the other block fills stage/barrier bubbles),
//   - 540 tiles distribute smoothly (~2.1/CU),
//   - schedule = r2's verified 3-buffer depth-2 counted-vmcnt loop, with
//     3 gl_lds16/thread (A 1 + B 2) -> WAITV(3).
// Ledger: top of K-step t, outstanding = stage(t)[3] + stage(t+1)[3];
// vmcnt(3) => stage(t) landed for THIS wave; the barrier (a) publishes
// everyone's stage(t), (b) all waves finished reading buffer (t+2)%3 at
// step t-1 before stage(t+2) overwrites it. Counted waits stay safe under
// any extra VMEM ops (they only strengthen the wait).
// MFMA operands SWAPPED (mfma(B,A) -> C^T in regs): 8B vector C stores.
// GATHER: A row = tok_list[off+m]; else off+m.
// Grid: blockIdx.x = ntile (0..3) -> each XCD sees one n0 panel (8 experts
// x 512 KB = 4 MB = its L2); blockIdx.y -> int4 work[] {e, m0, off, ne}.
template <int GATHER, int LEAKY>
__global__ __launch_bounds__(512, 4) void moe_gemm(
    const __bf16* __restrict__ A, const int* __restrict__ tok,
    const __bf16* __restrict__ W, const float* __restrict__ bias,
    const int4* __restrict__ work, const int* __restrict__ ntiles,
    __bf16* __restrict__ out) {
  if ((int)blockIdx.y >= ntiles[0]) return;
  const int4 wk = work[blockIdx.y];
  const int e = wk.x;
  const int m0 = wk.y;
  const int off = wk.z;
  const int ne = wk.w;
  const int n0 = blockIdx.x * 256;

  __shared__ __align__(16) __bf16 As[3][128 * 32];  // 8 KB each
  __shared__ __align__(16) __bf16 Bs[3][256 * 32];  // 16 KB each

  const int tid = threadIdx.x;
  const int lane = tid & 63;
  const int wid = tid >> 6;          // 0..7
  const int wm = wid >> 2, wn = wid & 3;
  const int ln = lane & 15, quad = lane >> 4;

  // A staging: chunk c = tid (0..511) -> row c>>2 (0..127), physical k-slot
  // c&3 holds logical k-chunk kc = (c&3) ^ ((row>>1)&3)  (XOR swizzle).
  const int arow = tid >> 2;
  const int kca = (tid & 3) ^ ((arow >> 1) & 3);
  int ra = m0 + arow;
  if (ra >= ne) ra = m0;  // clamp: garbage rows computed but never stored
  const long arowg = GATHER ? (long)tok[off + ra] : (long)(off + ra);
  const __bf16* aptr = A + arowg * DDIM + kca * 8;
  const int ast = wid * 512;  // wave-uniform elem offset in As[buf]

  // B staging: 2 chunks/thread, c = (wid*2+j)*64 + lane (0..1023), same map.
  const __bf16* bptr[2];
  int bst[2];
#pragma unroll
  for (int j = 0; j < 2; ++j) {
    const int c = (wid * 2 + j) * 64 + lane;
    const int row = c >> 2;                   // 0..255
    const int kc = (c & 3) ^ ((row >> 1) & 3);
    bptr[j] = W + ((long)e << 20) + (long)(n0 + row) * 1024 + kc * 8;
    bst[j] = (wid * 2 + j) * 512;
  }

  // Fragment-read swizzle: logical chunk quad of row r lives at physical
  // slot quad ^ ((r>>1)&3); row bases are 16-aligned so == (ln>>1)&3.
  const int swz = (quad ^ ((ln >> 1) & 3)) * 8;

  const f32x4_t vzero = {0.f, 0.f, 0.f, 0.f};
  f32x4_t acc[4][4];
#pragma unroll
  for (int i = 0; i < 4; ++i)
#pragma unroll
    for (int j = 0; j < 4; ++j) acc[i][j] = vzero;

#define STAGE(SB, KT)                                        \
  do {                                                       \
    const int k0_ = (KT) * 32;                               \
    gl_lds16(aptr + k0_, (__bf16*)As[SB] + ast);             \
    gl_lds16(bptr[0] + k0_, (__bf16*)Bs[SB] + bst[0]);       \
    gl_lds16(bptr[1] + k0_, (__bf16*)Bs[SB] + bst[1]);       \
  } while (0)

#define WAITB(N)                                             \
  do {                                                       \
    asm volatile("s_waitcnt vmcnt(" #N ")" ::: "memory");    \
    __builtin_amdgcn_s_barrier();                            \
  } while (0)

#define COMPUTE(CUR)                                                        \
  do {                                                                      \
    bf16x8_t aF[4], bF[4];                                                  \
    _Pragma("unroll") for (int i = 0; i < 4; ++i)                           \
        aF[i] = *(const bf16x8_t*)(&As[CUR][(wm * 64 + i * 16 + ln) * 32 +  \
                                            swz]);                          \
    _Pragma("unroll") for (int j = 0; j < 4; ++j)                           \
        bF[j] = *(const bf16x8_t*)(&Bs[CUR][(wn * 64 + j * 16 + ln) * 32 +  \
                                            swz]);                          \
    _Pragma("unroll") for (int i = 0; i < 4; ++i)                           \
        _Pragma("unroll") for (int j = 0; j < 4; ++j)                       \
            acc[i][j] = __builtin_amdgcn_mfma_f32_16x16x32_bf16(            \
                bF[j], aF[i], acc[i][j], 0, 0, 0);                          \
  } while (0)

  // Prologue: tiles 0 and 1 in flight (6 outstanding loads per thread).
  STAGE(0, 0);
  STAGE(1, 1);

  // Main loop: 30 K-steps, unrolled x3 so buffer indices are compile-time.
#pragma unroll 1
  for (int kt = 0; kt < 30; kt += 3) {
    WAITB(3); STAGE(2, kt + 2); COMPUTE(0);
    WAITB(3); STAGE(0, kt + 3); COMPUTE(1);
    WAITB(3); STAGE(1, kt + 4); COMPUTE(2);
  }
  // Peeled tail: tiles 30 (buf 0) and 31 (buf 1); no more stages.
  WAITB(3); COMPUTE(0);
  WAITB(0); COMPUTE(1);

#undef STAGE
#undef WAITB
#undef COMPUTE

  // Epilogue. Swapped-operand D layout: lane ln = output row (m), quad*4+r =
  // output col (n) within each 16x16 fragment -> 8B stores.
  const float* bs = bias + (e << 10);
  const int nb = n0 + wn * 64 + quad * 4;
  float4 bv[4];
#pragma unroll
  for (int j = 0; j < 4; ++j) bv[j] = *(const float4*)(bs + nb + j * 16);
#pragma unroll
  for (int i = 0; i < 4; ++i) {
    const int m = m0 + wm * 64 + i * 16 + ln;
    if (m < ne) {
      __bf16* orow = out + (size_t)(off + m) * 1024 + nb;
#pragma unroll
      for (int j = 0; j < 4; ++j) {
        float t0 = acc[i][j][0] + bv[j].x;
        float t1 = acc[i][j][1] + bv[j].y;
        float t2 = acc[i][j][2] + bv[j].z;
        float t3 = acc[i][j][3] + bv[j].w;
        if (LEAKY) {
          t0 = (t0 >= 0.f) ? t0 : 0.01f * t0;
          t1 = (t1 >= 0.f) ? t1 : 0.01f * t1;
          t2 = (t2 >= 0.f) ? t2 : 0.01f * t2;
          t3 = (t3 >= 0.f) ? t3 : 0.01f * t3;
        }
        bf16x4_t pk = {(__bf16)t0, (__bf16)t1, (__bf16)t2, (__bf16)t3};
        *(bf16x4_t*)(orow + j * 16) = pk;
      }
    }
  }
}

// ---------------------------------------------------------------------------
// Final combine: out[t] = wA*eo[slotA] + wB*eo[slotB]  (eo is bf16).
// 2048 blocks (4 tokens/block, one wave each), 16B loads.
__global__ __launch_bounds__(256) void combine_k(
    const __bf16* __restrict__ eo, const int* __restrict__ slot_of,
    const float* __restrict__ top_w, float* __restrict__ out) {
  const int t = blockIdx.x * 4 + (threadIdx.x >> 6);
  const int lane = threadIdx.x & 63;
  const int s1 = slot_of[t * 2], s2 = slot_of[t * 2 + 1];
  const float w1 = top_w[t * 2], w2 = top_w[t * 2 + 1];
  const bf16x8_t* r1 = (const bf16x8_t*)(eo + (size_t)s1 * DDIM);
  const bf16x8_t* r2 = (const bf16x8_t*)(eo + (size_t)s2 * DDIM);
  float4* o4 = (float4*)(out + (size_t)t * DDIM);
#pragma unroll
  for (int i = 0; i < 2; ++i) {
    const int idx = lane * 2 + i;  // bf16x8 chunk 0..127
    const bf16x8_t a = r1[idx];
    const bf16x8_t b = r2[idx];
    float4 o0, o1;
    o0.x = w1 * (float)a[0] + w2 * (float)b[0];
    o0.y = w1 * (float)a[1] + w2 * (float)b[1];
    o0.z = w1 * (float)a[2] + w2 * (float)b[2];
    o0.w = w1 * (float)a[3] + w2 * (float)b[3];
    o1.x = w1 * (float)a[4] + w2 * (float)b[4];
    o1.y = w1 * (float)a[5] + w2 * (float)b[5];
    o1.z = w1 * (float)a[6] + w2 * (float)b[6];
    o1.w = w1 * (float)a[7] + w2 * (float)b[7];
    o4[idx * 2] = o0;
    o4[idx * 2 + 1] = o1;
  }
}

// ---------------------------------------------------------------------------
extern "C" void kernel_launch(void* const* d_in, const int* in_sizes, int n_in,
                              void* d_out, int out_size, void* d_ws,
                              size_t ws_size, hipStream_t stream) {
  (void)in_sizes; (void)n_in; (void)out_size; (void)ws_size;
  const float* x  = (const float*)d_in[0];
  const float* gw = (const float*)d_in[1];
  const float* gb = (const float*)d_in[2];
  const float* w1 = (const float*)d_in[3];
  const float* b1 = (const float*)d_in[4];
  const float* w2 = (const float*)d_in[5];
  const float* b2 = (const float*)d_in[6];
  const float* w3 = (const float*)d_in[7];
  const float* b3 = (const float*)d_in[8];
  float* out = (float*)d_out;

  // Workspace carve-up (~150 MB total).
  uint8_t* p = (uint8_t*)d_ws;
  auto alloc = [&](size_t b) {
    uint8_t* r = p;
    p += (b + 255) & ~(size_t)255;
    return r;
  };
  int*    eoff     = (int*)alloc(4 * (EXPERTS + 1));
  int*    ntiles   = (int*)alloc(4);
  int4*   work     = (int4*)alloc(16 * MAXT);
  int*    top_i    = (int*)alloc(4ull * TOKENS * 2);
  float*  top_w    = (float*)alloc(4ull * TOKENS * 2);
  int*    slot_of  = (int*)alloc(4ull * TOKENS * 2);
  int*    tok_list = (int*)alloc(4ull * NSLOT);
  __bf16* xbf      = (__bf16*)alloc(2ull * TOKENS * DDIM);
  __bf16* w1T      = (__bf16*)alloc(2ull * EXPERTS * 1024 * 1024);
  __bf16* w2T      = (__bf16*)alloc(2ull * EXPERTS * 1024 * 1024);
  __bf16* w3T      = (__bf16*)alloc(2ull * EXPERTS * 1024 * 1024);
  __bf16* h1       = (__bf16*)alloc(2ull * NSLOT * 1024);
  __bf16* h2       = (__bf16*)alloc(2ull * NSLOT * 1024);
  __bf16* eo       = (__bf16*)alloc(2ull * NSLOT * 1024);

  gate_k<<<TOKENS / 4, 256, 0, stream>>>(x, gw, gb, xbf, top_i, top_w);
  twt_k<<<dim3(4, 16, 24), 256, 0, stream>>>(w1, w2, w3, w1T, w2T, w3T);
  plan_k<<<1, 1024, 0, stream>>>(top_i, eoff, tok_list, slot_of, work, ntiles);

  moe_gemm<1, 1><<<dim3(4, MAXT), 512, 0, stream>>>(
      xbf, tok_list, w1T, b1, work, ntiles, h1);
  moe_gemm<0, 1><<<dim3(4, MAXT), 512, 0, stream>>>(
      h1, tok_list, w2T, b2, work, ntiles, h2);
  moe_gemm<0, 0><<<dim3(4, MAXT), 512, 0, stream>>>(
      h2, tok_list, w3T, b3, work, ntiles, eo);

  combine_k<<<TOKENS / 4, 256, 0, stream>>>(eo, slot_of, top_w, out);
}